// Round 8
// baseline (359.572 us; speedup 1.0000x reference)
//
#include <hip/hip_runtime.h>
#include <hip/hip_bf16.h>

#define NROWS 400000
#define MSEL  100000
#define FDIM  128
#define D0 256
#define D1 256
#define D2 128

typedef __attribute__((ext_vector_type(8))) short short8;
typedef __attribute__((ext_vector_type(4))) float f32x4;
typedef __attribute__((ext_vector_type(4))) unsigned short ushort4v;
typedef __attribute__((ext_vector_type(2))) unsigned int uint2v;

__device__ __forceinline__ unsigned short f2bf(float f) {
    unsigned int u = __float_as_uint(f);
    unsigned int r = (u + 0x7fffu + ((u >> 16) & 1u)) >> 16;
    return (unsigned short)r;
}

// packed f32x2 -> bf16x2 via v_cvt_pk_bf16_f32
__device__ __forceinline__ unsigned int pk2bf(float a, float b) {
    __hip_bfloat162 h = __float22bfloat162_rn(make_float2(a, b));
    return *(unsigned int*)&h;
}

__device__ __forceinline__ float elu(float v) {
    return v > 0.f ? v : (__expf(v) - 1.f);
}

// ---------------------------------------------------------------------------
// Repack f32 weights into bf16 B-fragment order for mfma_f32_16x16x32_bf16.
// Tile (kt,nt) is 32x16; lane l holds B[kt*32+(l>>4)*8+j][nt*16+(l&15)], 8 bf16
// contiguous per lane.  ws: W0p [0,32768) shorts, W1p [32768,98304),
// W2p [98304,131072).
// ---------------------------------------------------------------------------
__global__ void pack_weights(const float* __restrict__ W0,
                             const float* __restrict__ W1,
                             const float* __restrict__ W2,
                             short* __restrict__ out) {
    int e = blockIdx.x * 256 + threadIdx.x;
    if (e >= 131072) return;
    const float* W; int N; int base; int le;
    if (e < 32768)       { W = W0; N = 256; base = 0;     le = e; }
    else if (e < 98304)  { W = W1; N = 256; base = 32768; le = e - 32768; }
    else                 { W = W2; N = 128; base = 98304; le = e - 98304; }
    int t    = le >> 9;
    int r    = le & 511;
    int lane = r >> 3;
    int j    = r & 7;
    int ntiles = N >> 4;
    int kt = t / ntiles, nt = t % ntiles;
    int k = kt * 32 + (lane >> 4) * 8 + j;
    int n = nt * 16 + (lane & 15);
    out[base + le] = (short)f2bf(W[k * N + n]);
}

__global__ void copy_x(const float4* __restrict__ x, float4* __restrict__ out, int n4) {
    int i = blockIdx.x * blockDim.x + threadIdx.x;
    int stride = gridDim.x * blockDim.x;
    for (; i < n4; i += stride) out[i] = x[i];
}

// ---------------------------------------------------------------------------
// Inverted index of sel: head[r] -> last j with sel[j]==r, next[j] -> chain.
// ---------------------------------------------------------------------------
__global__ void init_head(int* __restrict__ head) {
    int i = blockIdx.x * 256 + threadIdx.x;
    int s = gridDim.x * 256;
    for (; i < NROWS; i += s) head[i] = -1;
}

__global__ void build_links(const int* __restrict__ sel,
                            int* __restrict__ head, int* __restrict__ next) {
    int j = blockIdx.x * 256 + threadIdx.x;
    if (j < MSEL) {
        int r = sel[j];
        next[j] = atomicExch(head + r, j);
    }
}

// ---------------------------------------------------------------------------
// Heterogeneous kernel: two block roles interleaved by blockIdx so both run
// concurrently on every CU from t=0 (R7 lesson: a post-barrier copy tail
// inherits the latency-bound issue pattern; independent blocks don't).
//   role MLP  (bid&3 != 3, mlpIdx=(bid>>2)*3+(bid&3) in [0,3125)):
//     gather 32 rows -> 3-layer ELU MLP (bf16 MFMA) -> up tile staged in LDS
//     -> ONE coalesced 8KB burst to up[] (R4 wrote 32B partials: 44MB for
//     25.6MB of data).
//   role COPY (bid&3 == 3, c=bid>>2 in [0,1041)): grid-stride streaming copy
//     of untouched rows (head<0): out[row]=x[row].  ~310MB with no
//     dependency on the MLP -> true overlap.
// LDS 32KB: x [0,4096) sh, h0 [4096,12288), h1 rows0-15 [12288,16384),
// rows16-31 [0,4096) (overlay; x dead after layer 0).
// XOR swizzle shortIdx ^= (row&7)<<3 breaks ds_read_b128 bank conflicts.
// NO launch_bounds wave cap (R6: forcing VGPR<=102 -> spill catastrophe).
// ---------------------------------------------------------------------------
template <bool SPLIT>
__global__ __launch_bounds__(256) void mlp_hetero(
    const float* __restrict__ x, const int* __restrict__ sel,
    const short* __restrict__ wp,
    const float* __restrict__ b0v, const float* __restrict__ b1v,
    const float* __restrict__ b2v,
    const int* __restrict__ head,
    unsigned short* __restrict__ upOut, float* __restrict__ out) {
    __shared__ __align__(16) short lds[16384];

    const int tid = threadIdx.x;
    const int bid = blockIdx.x;

    if (SPLIT && ((bid & 3) == 3)) {
        // ===== COPY role: stream untouched rows =====
        const int c = bid >> 2;                 // 0..1040
        const float4* x4 = (const float4*)x;
        float4* o4 = (float4*)out;
        const int stride = 1041 * 256;
        for (int g = c * 256 + tid; g < NROWS * 32; g += stride) {
            int row = g >> 5;
            if (head[row] < 0) o4[g] = x4[g];
        }
        return;
    }

    const int mlpIdx = SPLIT ? ((bid >> 2) * 3 + (bid & 3)) : bid;
    if (mlpIdx >= MSEL / 32) return;

    const int lane = tid & 63;
    const int w    = tid >> 6;
    const int rowBase = mlpIdx * 32;
    const int lm = lane & 15;
    const int kq = lane >> 4;
    const int sxz = (lm & 7) << 3;

    const short* W0p = wp;
    const short* W1p = wp + 32768;
    const short* W2p = wp + 98304;

    // prefetch layer-0 B fragments (hide under gather)
    short8 B0[4][4];
    #pragma unroll
    for (int kt = 0; kt < 4; kt++)
        #pragma unroll
        for (int ntl = 0; ntl < 4; ntl++)
            B0[kt][ntl] = *(const short8*)(W0p + ((kt * 16 + (w * 4 + ntl)) * 512 + lane * 8));

    // gather: 32 rows x 128 f32 -> bf16 into LDS
    const float4* xv = (const float4*)x;
    #pragma unroll
    for (int it = 0; it < 4; it++) {
        int i = it * 256 + tid;
        int row = i >> 5, seg = i & 31;
        float4 v = xv[(size_t)sel[rowBase + row] * 32 + seg];
        uint2v p = { pk2bf(v.x, v.y), pk2bf(v.z, v.w) };
        *(uint2v*)(&lds[(row * 128 + seg * 4) ^ ((row & 7) << 3)]) = p;
    }
    __syncthreads();

    const f32x4 zero4 = {0.f, 0.f, 0.f, 0.f};

    // ===== layer 0: (32x128) @ W0(128x256) =====
    {
        f32x4 acc[2][4];
        #pragma unroll
        for (int i = 0; i < 2; i++)
            #pragma unroll
            for (int j = 0; j < 4; j++) acc[i][j] = zero4;
        #pragma unroll
        for (int rt = 0; rt < 2; rt++) {
            short8 a[4];
            int rowA = rt * 16 + lm;
            #pragma unroll
            for (int kt = 0; kt < 4; kt++)
                a[kt] = *(const short8*)(&lds[(rowA * 128 + kt * 32 + kq * 8) ^ sxz]);
            #pragma unroll
            for (int ntl = 0; ntl < 4; ntl++)
                #pragma unroll
                for (int kt = 0; kt < 4; kt++)
                    acc[rt][ntl] = __builtin_amdgcn_mfma_f32_16x16x32_bf16(a[kt], B0[kt][ntl], acc[rt][ntl], 0, 0, 0);
        }
        #pragma unroll
        for (int ntl = 0; ntl < 4; ntl++) {
            int col = (w * 4 + ntl) * 16 + lm;
            float bias = b0v[col];
            #pragma unroll
            for (int rt = 0; rt < 2; rt++) {
                float v0 = elu(acc[rt][ntl][0] + bias);
                float v1 = elu(acc[rt][ntl][1] + bias);
                float v2 = elu(acc[rt][ntl][2] + bias);
                float v3 = elu(acc[rt][ntl][3] + bias);
                unsigned int u01 = pk2bf(v0, v1), u23 = pk2bf(v2, v3);
                int row = rt * 16 + kq * 4;
                lds[4096 + (((row+0) * 256 + col) ^ (((row+0) & 7) << 3))] = (short)(u01 & 0xffff);
                lds[4096 + (((row+1) * 256 + col) ^ (((row+1) & 7) << 3))] = (short)(u01 >> 16);
                lds[4096 + (((row+2) * 256 + col) ^ (((row+2) & 7) << 3))] = (short)(u23 & 0xffff);
                lds[4096 + (((row+3) * 256 + col) ^ (((row+3) & 7) << 3))] = (short)(u23 >> 16);
            }
        }
    }
    __syncthreads();

    // ===== layer 1: (32x256) @ W1(256x256), 2 col-passes =====
    // h1 overlay: rows 0-15 -> [12288,16384), rows 16-31 -> [0,4096)
    #pragma unroll
    for (int pass = 0; pass < 2; pass++) {
        short8 B1[8][2];
        #pragma unroll
        for (int kt = 0; kt < 8; kt++)
            #pragma unroll
            for (int p = 0; p < 2; p++)
                B1[kt][p] = *(const short8*)(W1p + ((kt * 16 + (w * 4 + pass * 2 + p)) * 512 + lane * 8));
        f32x4 acc[2][2];
        #pragma unroll
        for (int i = 0; i < 2; i++)
            #pragma unroll
            for (int j = 0; j < 2; j++) acc[i][j] = zero4;
        #pragma unroll
        for (int rt = 0; rt < 2; rt++) {
            short8 a[8];
            int rowA = rt * 16 + lm;
            #pragma unroll
            for (int kt = 0; kt < 8; kt++)
                a[kt] = *(const short8*)(&lds[4096 + ((rowA * 256 + kt * 32 + kq * 8) ^ sxz)]);
            #pragma unroll
            for (int p = 0; p < 2; p++)
                #pragma unroll
                for (int kt = 0; kt < 8; kt++)
                    acc[rt][p] = __builtin_amdgcn_mfma_f32_16x16x32_bf16(a[kt], B1[kt][p], acc[rt][p], 0, 0, 0);
        }
        #pragma unroll
        for (int p = 0; p < 2; p++) {
            int col = (w * 4 + pass * 2 + p) * 16 + lm;
            float bias = b1v[col];
            #pragma unroll
            for (int rt = 0; rt < 2; rt++) {
                float v0 = elu(acc[rt][p][0] + bias);
                float v1 = elu(acc[rt][p][1] + bias);
                float v2 = elu(acc[rt][p][2] + bias);
                float v3 = elu(acc[rt][p][3] + bias);
                unsigned int u01 = pk2bf(v0, v1), u23 = pk2bf(v2, v3);
                int row = rt * 16 + kq * 4;
                int hb = rt ? 0 : 12288;   // overlay base
                lds[hb + ((((row+0) & 15) * 256 + col) ^ (((row+0) & 7) << 3))] = (short)(u01 & 0xffff);
                lds[hb + ((((row+1) & 15) * 256 + col) ^ (((row+1) & 7) << 3))] = (short)(u01 >> 16);
                lds[hb + ((((row+2) & 15) * 256 + col) ^ (((row+2) & 7) << 3))] = (short)(u23 & 0xffff);
                lds[hb + ((((row+3) & 15) * 256 + col) ^ (((row+3) & 7) << 3))] = (short)(u23 >> 16);
            }
        }
    }
    __syncthreads();

    // ===== layer 2: (32x256) @ W2(256x128) =====
    {
        short8 B2[8][2];
        #pragma unroll
        for (int kt = 0; kt < 8; kt++)
            #pragma unroll
            for (int ntl = 0; ntl < 2; ntl++)
                B2[kt][ntl] = *(const short8*)(W2p + ((kt * 8 + (w * 2 + ntl)) * 512 + lane * 8));

        f32x4 acc[2][2];
        #pragma unroll
        for (int i = 0; i < 2; i++)
            #pragma unroll
            for (int j = 0; j < 2; j++) acc[i][j] = zero4;
        #pragma unroll
        for (int rt = 0; rt < 2; rt++) {
            short8 a[8];
            int rowA = rt * 16 + lm;
            int hb = rt ? 0 : 12288;
            #pragma unroll
            for (int kt = 0; kt < 8; kt++)
                a[kt] = *(const short8*)(&lds[hb + (((rowA & 15) * 256 + kt * 32 + kq * 8) ^ sxz)]);
            #pragma unroll
            for (int ntl = 0; ntl < 2; ntl++)
                #pragma unroll
                for (int kt = 0; kt < 8; kt++)
                    acc[rt][ntl] = __builtin_amdgcn_mfma_f32_16x16x32_bf16(a[kt], B2[kt][ntl], acc[rt][ntl], 0, 0, 0);
        }
        // epilogue 2: bias+ELU -> stage up tile in LDS (h0 region, free now)
        #pragma unroll
        for (int ntl = 0; ntl < 2; ntl++) {
            int col = (w * 2 + ntl) * 16 + lm;
            float bias = b2v[col];
            #pragma unroll
            for (int rt = 0; rt < 2; rt++)
                #pragma unroll
                for (int r = 0; r < 4; r++) {
                    int row = rt * 16 + kq * 4 + r;
                    float v = elu(acc[rt][ntl][r] + bias);
                    if (SPLIT) {
                        lds[4096 + row * 128 + col] = (short)f2bf(v);
                    } else {
                        atomicAdd(out + (size_t)sel[rowBase + row] * 128 + col, v);
                    }
                }
        }
    }
    if (SPLIT) {
        __syncthreads();
        // coalesced up write: 32 rows x 256B = 8KB contiguous, 2 dwordx4/thr
        const short8* s8 = (const short8*)(&lds[4096]);
        short8* u8 = (short8*)(upOut + (size_t)rowBase * 128);
        u8[tid]       = s8[tid];
        u8[tid + 256] = s8[tid + 256];
    }
}

// ---------------------------------------------------------------------------
// merge: wave per TOUCHED row (head>=0): out[r] = x[r] + sum_{chain} up[j].
// Untouched rows were copied by the hetero kernel's COPY blocks.  No atomics.
// ---------------------------------------------------------------------------
__global__ __launch_bounds__(256) void merge_touched(
    const float2* __restrict__ x2, const unsigned int* __restrict__ up32,
    const int* __restrict__ head, const int* __restrict__ next,
    float2* __restrict__ out2) {
    int wid  = blockIdx.x * 4 + (threadIdx.x >> 6);
    int lane = threadIdx.x & 63;
    int wstride = gridDim.x * 4;
    for (int row = wid; row < NROWS; row += wstride) {
        int j = head[row];
        if (j < 0) continue;
        float2 v = x2[(size_t)row * 64 + lane];
        do {
            unsigned int u = up32[(size_t)j * 64 + lane];
            v.x += __uint_as_float(u << 16);
            v.y += __uint_as_float(u & 0xffff0000u);
            j = next[j];
        } while (j >= 0);
        out2[(size_t)row * 64 + lane] = v;
    }
}

extern "C" void kernel_launch(void* const* d_in, const int* in_sizes, int n_in,
                              void* d_out, int out_size, void* d_ws, size_t ws_size,
                              hipStream_t stream) {
    const float* x   = (const float*)d_in[0];
    const int*   sel = (const int*)d_in[1];
    const float* W0  = (const float*)d_in[2];
    const float* b0  = (const float*)d_in[3];
    const float* W1  = (const float*)d_in[4];
    const float* b1  = (const float*)d_in[5];
    const float* W2  = (const float*)d_in[6];
    const float* b2  = (const float*)d_in[7];
    float* out = (float*)d_out;

    char* wsb = (char*)d_ws;
    short* wp          = (short*)wsb;                                  // 262144 B
    unsigned short* up = (unsigned short*)(wsb + 262144);              // 25.6 MB
    int* head          = (int*)(wsb + 262144 + (size_t)MSEL * 256);    // 1.6 MB
    int* nxt           = head + NROWS;                                 // 0.4 MB
    const size_t need  = 262144 + (size_t)MSEL * 256 + (size_t)NROWS * 4 + (size_t)MSEL * 4;

    pack_weights<<<512, 256, 0, stream>>>(W0, W1, W2, wp);
    if (ws_size >= need) {
        init_head<<<1024, 256, 0, stream>>>(head);
        build_links<<<(MSEL + 255) / 256, 256, 0, stream>>>(sel, head, nxt);
        // 3125 MLP blocks + 1041 COPY blocks, interleaved 3:1
        mlp_hetero<true><<<4167, 256, 0, stream>>>(x, sel, wp, b0, b1, b2, head, up, out);
        merge_touched<<<4096, 256, 0, stream>>>((const float2*)x, (const unsigned int*)up,
                                                head, nxt, (float2*)out);
    } else {
        copy_x<<<4096, 256, 0, stream>>>((const float4*)x, (float4*)out, NROWS * FDIM / 4);
        mlp_hetero<false><<<MSEL / 32, 256, 0, stream>>>(x, sel, wp, b0, b1, b2, head, up, out);
    }
}

// Round 9
// 160.844 us; speedup vs baseline: 2.2355x; 2.2355x over previous
//
#include <hip/hip_runtime.h>
#include <hip/hip_bf16.h>

#define NROWS 400000
#define MSEL  100000
#define FDIM  128
#define D0 256
#define D1 256
#define D2 128

typedef __attribute__((ext_vector_type(8))) short short8;
typedef __attribute__((ext_vector_type(4))) float f32x4;
typedef __attribute__((ext_vector_type(4))) unsigned short ushort4v;
typedef __attribute__((ext_vector_type(2))) unsigned int uint2v;

__device__ __forceinline__ unsigned short f2bf(float f) {
    unsigned int u = __float_as_uint(f);
    unsigned int r = (u + 0x7fffu + ((u >> 16) & 1u)) >> 16;
    return (unsigned short)r;
}

// packed f32x2 -> bf16x2 via v_cvt_pk_bf16_f32
__device__ __forceinline__ unsigned int pk2bf(float a, float b) {
    __hip_bfloat162 h = __float22bfloat162_rn(make_float2(a, b));
    return *(unsigned int*)&h;
}

__device__ __forceinline__ float elu(float v) {
    return v > 0.f ? v : (__expf(v) - 1.f);
}

// ---------------------------------------------------------------------------
// Repack f32 weights into bf16 B-fragment order for mfma_f32_16x16x32_bf16.
// Tile (kt,nt) is 32x16; lane l holds B[kt*32+(l>>4)*8+j][nt*16+(l&15)], 8 bf16
// contiguous per lane.  ws: W0p [0,32768) shorts, W1p [32768,98304),
// W2p [98304,131072).
// ---------------------------------------------------------------------------
__global__ void pack_weights(const float* __restrict__ W0,
                             const float* __restrict__ W1,
                             const float* __restrict__ W2,
                             short* __restrict__ out) {
    int e = blockIdx.x * 256 + threadIdx.x;
    if (e >= 131072) return;
    const float* W; int N; int base; int le;
    if (e < 32768)       { W = W0; N = 256; base = 0;     le = e; }
    else if (e < 98304)  { W = W1; N = 256; base = 32768; le = e - 32768; }
    else                 { W = W2; N = 128; base = 98304; le = e - 98304; }
    int t    = le >> 9;
    int r    = le & 511;
    int lane = r >> 3;
    int j    = r & 7;
    int ntiles = N >> 4;
    int kt = t / ntiles, nt = t % ntiles;
    int k = kt * 32 + (lane >> 4) * 8 + j;
    int n = nt * 16 + (lane & 15);
    out[base + le] = (short)f2bf(W[k * N + n]);
}

__global__ void copy_x(const float4* __restrict__ x, float4* __restrict__ out, int n4) {
    int i = blockIdx.x * blockDim.x + threadIdx.x;
    int stride = gridDim.x * blockDim.x;
    for (; i < n4; i += stride) out[i] = x[i];
}

// ---------------------------------------------------------------------------
// Inverted index of sel: head[r] -> last j with sel[j]==r, next[j] -> chain.
// ---------------------------------------------------------------------------
__global__ void init_head(int* __restrict__ head) {
    int i = blockIdx.x * 256 + threadIdx.x;
    int s = gridDim.x * 256;
    for (; i < NROWS; i += s) head[i] = -1;
}

__global__ void build_links(const int* __restrict__ sel,
                            int* __restrict__ head, int* __restrict__ next) {
    int j = blockIdx.x * 256 + threadIdx.x;
    if (j < MSEL) {
        int r = sel[j];
        next[j] = atomicExch(head + r, j);
    }
}

// ---------------------------------------------------------------------------
// Fused gather -> 3-layer ELU MLP (bf16 MFMA) -> up burst + pipelined x->out
// slice copy.  Block = 256 thr = 4 waves, 32 selected rows + a 128-row copy
// slice (3125 x 128 = 400000 exactly).
// Copy is register-staged and software-pipelined (T14): 4 chunks x 4 float4
// per thread; loads issue right after a barrier, the next layer's MFMA/LDS
// phase covers their ~900cyc HBM latency, stores drain at the next barrier.
// Copy is UNCONDITIONAL (no head[] check); merge_touched later overwrites
// touched rows.  R7 failed with a serial post-barrier tail; R8 failed with
// dedicated copy blocks (LDS-slot starvation) — same waves + latency hiding
// is the remaining overlap structure.
// LDS 32KB: x [0,4096) sh, h0 [4096,12288), h1 rows0-15 [12288,16384),
// rows16-31 [0,4096) (overlay; x dead after layer 0).
// XOR swizzle shortIdx ^= (row&7)<<3 breaks ds_read_b128 bank conflicts.
// NO launch_bounds wave cap (R6: VGPR<=102 forced -> spill catastrophe).
// ---------------------------------------------------------------------------
template <bool SPLIT>
__global__ __launch_bounds__(256) void mlp_fused(
    const float* __restrict__ x, const int* __restrict__ sel,
    const short* __restrict__ wp,
    const float* __restrict__ b0v, const float* __restrict__ b1v,
    const float* __restrict__ b2v,
    unsigned short* __restrict__ upOut, float* __restrict__ out) {
    __shared__ __align__(16) short lds[16384];

    const int tid  = threadIdx.x;
    const int lane = tid & 63;
    const int w    = tid >> 6;
    const int rowBase = blockIdx.x * 32;
    const int lm = lane & 15;
    const int kq = lane >> 4;
    const int sxz = (lm & 7) << 3;

    const short* W0p = wp;
    const short* W1p = wp + 32768;
    const short* W2p = wp + 98304;

    // copy-slice pointers (128 rows = 4096 float4 per block)
    const float4* xs = (const float4*)x + (size_t)blockIdx.x * 4096;
    float4* os = (float4*)out + (size_t)blockIdx.x * 4096;
    float4 cc0, cc1, cc2, cc3;
#define LOADC(c)  { int b_ = (c) * 1024 + tid; cc0 = xs[b_]; cc1 = xs[b_ + 256]; \
                    cc2 = xs[b_ + 512]; cc3 = xs[b_ + 768]; }
#define STOREC(c) { int b_ = (c) * 1024 + tid; os[b_] = cc0; os[b_ + 256] = cc1; \
                    os[b_ + 512] = cc2; os[b_ + 768] = cc3; }

    // prefetch layer-0 B fragments (hide under gather)
    short8 B0[4][4];
    #pragma unroll
    for (int kt = 0; kt < 4; kt++)
        #pragma unroll
        for (int ntl = 0; ntl < 4; ntl++)
            B0[kt][ntl] = *(const short8*)(W0p + ((kt * 16 + (w * 4 + ntl)) * 512 + lane * 8));

    // gather: 32 rows x 128 f32 -> bf16 into LDS
    const float4* xv = (const float4*)x;
    #pragma unroll
    for (int it = 0; it < 4; it++) {
        int i = it * 256 + tid;
        int row = i >> 5, seg = i & 31;
        float4 v = xv[(size_t)sel[rowBase + row] * 32 + seg];
        uint2v p = { pk2bf(v.x, v.y), pk2bf(v.z, v.w) };
        *(uint2v*)(&lds[(row * 128 + seg * 4) ^ ((row & 7) << 3)]) = p;
    }
    __syncthreads();

    if (SPLIT) LOADC(0);          // chunk0 loads hide under layer 0

    const f32x4 zero4 = {0.f, 0.f, 0.f, 0.f};

    // ===== layer 0: (32x128) @ W0(128x256) =====
    {
        f32x4 acc[2][4];
        #pragma unroll
        for (int i = 0; i < 2; i++)
            #pragma unroll
            for (int j = 0; j < 4; j++) acc[i][j] = zero4;
        #pragma unroll
        for (int rt = 0; rt < 2; rt++) {
            short8 a[4];
            int rowA = rt * 16 + lm;
            #pragma unroll
            for (int kt = 0; kt < 4; kt++)
                a[kt] = *(const short8*)(&lds[(rowA * 128 + kt * 32 + kq * 8) ^ sxz]);
            #pragma unroll
            for (int ntl = 0; ntl < 4; ntl++)
                #pragma unroll
                for (int kt = 0; kt < 4; kt++)
                    acc[rt][ntl] = __builtin_amdgcn_mfma_f32_16x16x32_bf16(a[kt], B0[kt][ntl], acc[rt][ntl], 0, 0, 0);
        }
        #pragma unroll
        for (int ntl = 0; ntl < 4; ntl++) {
            int col = (w * 4 + ntl) * 16 + lm;
            float bias = b0v[col];
            #pragma unroll
            for (int rt = 0; rt < 2; rt++) {
                float v0 = elu(acc[rt][ntl][0] + bias);
                float v1 = elu(acc[rt][ntl][1] + bias);
                float v2 = elu(acc[rt][ntl][2] + bias);
                float v3 = elu(acc[rt][ntl][3] + bias);
                unsigned int u01 = pk2bf(v0, v1), u23 = pk2bf(v2, v3);
                int row = rt * 16 + kq * 4;
                lds[4096 + (((row+0) * 256 + col) ^ (((row+0) & 7) << 3))] = (short)(u01 & 0xffff);
                lds[4096 + (((row+1) * 256 + col) ^ (((row+1) & 7) << 3))] = (short)(u01 >> 16);
                lds[4096 + (((row+2) * 256 + col) ^ (((row+2) & 7) << 3))] = (short)(u23 & 0xffff);
                lds[4096 + (((row+3) * 256 + col) ^ (((row+3) & 7) << 3))] = (short)(u23 >> 16);
            }
        }
    }
    __syncthreads();

    if (SPLIT) { STOREC(0); LOADC(1); }   // chunk1 hides under L1 pass 0

    // ===== layer 1: (32x256) @ W1(256x256), 2 col-passes =====
    // h1 overlay: rows 0-15 -> [12288,16384), rows 16-31 -> [0,4096)
    #pragma unroll
    for (int pass = 0; pass < 2; pass++) {
        short8 B1[8][2];
        #pragma unroll
        for (int kt = 0; kt < 8; kt++)
            #pragma unroll
            for (int p = 0; p < 2; p++)
                B1[kt][p] = *(const short8*)(W1p + ((kt * 16 + (w * 4 + pass * 2 + p)) * 512 + lane * 8));
        f32x4 acc[2][2];
        #pragma unroll
        for (int i = 0; i < 2; i++)
            #pragma unroll
            for (int j = 0; j < 2; j++) acc[i][j] = zero4;
        #pragma unroll
        for (int rt = 0; rt < 2; rt++) {
            short8 a[8];
            int rowA = rt * 16 + lm;
            #pragma unroll
            for (int kt = 0; kt < 8; kt++)
                a[kt] = *(const short8*)(&lds[4096 + ((rowA * 256 + kt * 32 + kq * 8) ^ sxz)]);
            #pragma unroll
            for (int p = 0; p < 2; p++)
                #pragma unroll
                for (int kt = 0; kt < 8; kt++)
                    acc[rt][p] = __builtin_amdgcn_mfma_f32_16x16x32_bf16(a[kt], B1[kt][p], acc[rt][p], 0, 0, 0);
        }
        #pragma unroll
        for (int p = 0; p < 2; p++) {
            int col = (w * 4 + pass * 2 + p) * 16 + lm;
            float bias = b1v[col];
            #pragma unroll
            for (int rt = 0; rt < 2; rt++) {
                float v0 = elu(acc[rt][p][0] + bias);
                float v1 = elu(acc[rt][p][1] + bias);
                float v2 = elu(acc[rt][p][2] + bias);
                float v3 = elu(acc[rt][p][3] + bias);
                unsigned int u01 = pk2bf(v0, v1), u23 = pk2bf(v2, v3);
                int row = rt * 16 + kq * 4;
                int hb = rt ? 0 : 12288;   // overlay base
                lds[hb + ((((row+0) & 15) * 256 + col) ^ (((row+0) & 7) << 3))] = (short)(u01 & 0xffff);
                lds[hb + ((((row+1) & 15) * 256 + col) ^ (((row+1) & 7) << 3))] = (short)(u01 >> 16);
                lds[hb + ((((row+2) & 15) * 256 + col) ^ (((row+2) & 7) << 3))] = (short)(u23 & 0xffff);
                lds[hb + ((((row+3) & 15) * 256 + col) ^ (((row+3) & 7) << 3))] = (short)(u23 >> 16);
            }
        }
        if (SPLIT && pass == 0) { STOREC(1); LOADC(2); }   // chunk2 hides under pass 1
    }
    __syncthreads();

    if (SPLIT) { STOREC(2); LOADC(3); }   // chunk3 hides under layer 2

    // ===== layer 2: (32x256) @ W2(256x128) =====
    {
        short8 B2[8][2];
        #pragma unroll
        for (int kt = 0; kt < 8; kt++)
            #pragma unroll
            for (int ntl = 0; ntl < 2; ntl++)
                B2[kt][ntl] = *(const short8*)(W2p + ((kt * 8 + (w * 2 + ntl)) * 512 + lane * 8));

        f32x4 acc[2][2];
        #pragma unroll
        for (int i = 0; i < 2; i++)
            #pragma unroll
            for (int j = 0; j < 2; j++) acc[i][j] = zero4;
        #pragma unroll
        for (int rt = 0; rt < 2; rt++) {
            short8 a[8];
            int rowA = rt * 16 + lm;
            int hb = rt ? 0 : 12288;
            #pragma unroll
            for (int kt = 0; kt < 8; kt++)
                a[kt] = *(const short8*)(&lds[hb + (((rowA & 15) * 256 + kt * 32 + kq * 8) ^ sxz)]);
            #pragma unroll
            for (int ntl = 0; ntl < 2; ntl++)
                #pragma unroll
                for (int kt = 0; kt < 8; kt++)
                    acc[rt][ntl] = __builtin_amdgcn_mfma_f32_16x16x32_bf16(a[kt], B2[kt][ntl], acc[rt][ntl], 0, 0, 0);
        }
        // epilogue 2: bias+ELU -> stage up tile in LDS (h0 region, free now)
        #pragma unroll
        for (int ntl = 0; ntl < 2; ntl++) {
            int col = (w * 2 + ntl) * 16 + lm;
            float bias = b2v[col];
            #pragma unroll
            for (int rt = 0; rt < 2; rt++)
                #pragma unroll
                for (int r = 0; r < 4; r++) {
                    int row = rt * 16 + kq * 4 + r;
                    float v = elu(acc[rt][ntl][r] + bias);
                    if (SPLIT) {
                        lds[4096 + row * 128 + col] = (short)f2bf(v);
                    } else {
                        atomicAdd(out + (size_t)sel[rowBase + row] * 128 + col, v);
                    }
                }
        }
    }
    if (SPLIT) {
        __syncthreads();
        // coalesced up write: 32 rows x 256B = 8KB contiguous, 2 dwordx4/thr
        const short8* s8 = (const short8*)(&lds[4096]);
        short8* u8 = (short8*)(upOut + (size_t)rowBase * 128);
        u8[tid]       = s8[tid];
        u8[tid + 256] = s8[tid + 256];
        STOREC(3);
    }
#undef LOADC
#undef STOREC
}

// ---------------------------------------------------------------------------
// merge: wave per TOUCHED row (head>=0): out[r] = x[r] + sum_{chain} up[j].
// Untouched rows were written by mlp_fused's pipelined copy (touched ones
// too — harmlessly; we overwrite them here).  No atomics.
// ---------------------------------------------------------------------------
__global__ __launch_bounds__(256) void merge_touched(
    const float2* __restrict__ x2, const unsigned int* __restrict__ up32,
    const int* __restrict__ head, const int* __restrict__ next,
    float2* __restrict__ out2) {
    int wid  = blockIdx.x * 4 + (threadIdx.x >> 6);
    int lane = threadIdx.x & 63;
    int wstride = gridDim.x * 4;
    for (int row = wid; row < NROWS; row += wstride) {
        int j = head[row];
        if (j < 0) continue;
        float2 v = x2[(size_t)row * 64 + lane];
        do {
            unsigned int u = up32[(size_t)j * 64 + lane];
            v.x += __uint_as_float(u << 16);
            v.y += __uint_as_float(u & 0xffff0000u);
            j = next[j];
        } while (j >= 0);
        out2[(size_t)row * 64 + lane] = v;
    }
}

extern "C" void kernel_launch(void* const* d_in, const int* in_sizes, int n_in,
                              void* d_out, int out_size, void* d_ws, size_t ws_size,
                              hipStream_t stream) {
    const float* x   = (const float*)d_in[0];
    const int*   sel = (const int*)d_in[1];
    const float* W0  = (const float*)d_in[2];
    const float* b0  = (const float*)d_in[3];
    const float* W1  = (const float*)d_in[4];
    const float* b1  = (const float*)d_in[5];
    const float* W2  = (const float*)d_in[6];
    const float* b2  = (const float*)d_in[7];
    float* out = (float*)d_out;

    char* wsb = (char*)d_ws;
    short* wp          = (short*)wsb;                                  // 262144 B
    unsigned short* up = (unsigned short*)(wsb + 262144);              // 25.6 MB
    int* head          = (int*)(wsb + 262144 + (size_t)MSEL * 256);    // 1.6 MB
    int* nxt           = head + NROWS;                                 // 0.4 MB
    const size_t need  = 262144 + (size_t)MSEL * 256 + (size_t)NROWS * 4 + (size_t)MSEL * 4;

    pack_weights<<<512, 256, 0, stream>>>(W0, W1, W2, wp);
    if (ws_size >= need) {
        init_head<<<1024, 256, 0, stream>>>(head);
        build_links<<<(MSEL + 255) / 256, 256, 0, stream>>>(sel, head, nxt);
        mlp_fused<true><<<MSEL / 32, 256, 0, stream>>>(x, sel, wp, b0, b1, b2, up, out);
        merge_touched<<<4096, 256, 0, stream>>>((const float2*)x, (const unsigned int*)up,
                                                head, nxt, (float2*)out);
    } else {
        copy_x<<<4096, 256, 0, stream>>>((const float4*)x, (float4*)out, NROWS * FDIM / 4);
        mlp_fused<false><<<MSEL / 32, 256, 0, stream>>>(x, sel, wp, b0, b1, b2, up, out);
    }
}

// Round 10
// 151.306 us; speedup vs baseline: 2.3764x; 1.0630x over previous
//
#include <hip/hip_runtime.h>
#include <hip/hip_bf16.h>

#define NROWS 400000
#define MSEL  100000
#define FDIM  128
#define D0 256
#define D1 256
#define D2 128

typedef __attribute__((ext_vector_type(8))) short short8;
typedef __attribute__((ext_vector_type(4))) float f32x4;
typedef __attribute__((ext_vector_type(4))) unsigned short ushort4v;
typedef __attribute__((ext_vector_type(2))) unsigned int uint2v;

__device__ __forceinline__ unsigned short f2bf(float f) {
    unsigned int u = __float_as_uint(f);
    unsigned int r = (u + 0x7fffu + ((u >> 16) & 1u)) >> 16;
    return (unsigned short)r;
}

// packed f32x2 -> bf16x2 via v_cvt_pk_bf16_f32
__device__ __forceinline__ unsigned int pk2bf(float a, float b) {
    __hip_bfloat162 h = __float22bfloat162_rn(make_float2(a, b));
    return *(unsigned int*)&h;
}

__device__ __forceinline__ float elu(float v) {
    return v > 0.f ? v : (__expf(v) - 1.f);
}

// ---------------------------------------------------------------------------
// Repack f32 weights into bf16 B-fragment order for mfma_f32_16x16x32_bf16.
// Tile (kt,nt) is 32x16; lane l holds B[kt*32+(l>>4)*8+j][nt*16+(l&15)], 8 bf16
// contiguous per lane.  ws: W0p [0,32768) shorts, W1p [32768,98304),
// W2p [98304,131072).
// ---------------------------------------------------------------------------
__global__ void pack_weights(const float* __restrict__ W0,
                             const float* __restrict__ W1,
                             const float* __restrict__ W2,
                             short* __restrict__ out) {
    int e = blockIdx.x * 256 + threadIdx.x;
    if (e >= 131072) return;
    const float* W; int N; int base; int le;
    if (e < 32768)       { W = W0; N = 256; base = 0;     le = e; }
    else if (e < 98304)  { W = W1; N = 256; base = 32768; le = e - 32768; }
    else                 { W = W2; N = 128; base = 98304; le = e - 98304; }
    int t    = le >> 9;
    int r    = le & 511;
    int lane = r >> 3;
    int j    = r & 7;
    int ntiles = N >> 4;
    int kt = t / ntiles, nt = t % ntiles;
    int k = kt * 32 + (lane >> 4) * 8 + j;
    int n = nt * 16 + (lane & 15);
    out[base + le] = (short)f2bf(W[k * N + n]);
}

__global__ void copy_x(const float4* __restrict__ x, float4* __restrict__ out, int n4) {
    int i = blockIdx.x * blockDim.x + threadIdx.x;
    int stride = gridDim.x * blockDim.x;
    for (; i < n4; i += stride) out[i] = x[i];
}

// ---------------------------------------------------------------------------
// Inverted index of sel: head[r] -> last j with sel[j]==r, next[j] -> chain.
// ---------------------------------------------------------------------------
__global__ void init_head(int* __restrict__ head) {
    int i = blockIdx.x * 256 + threadIdx.x;
    int s = gridDim.x * 256;
    for (; i < NROWS; i += s) head[i] = -1;
}

__global__ void build_links(const int* __restrict__ sel,
                            int* __restrict__ head, int* __restrict__ next) {
    int j = blockIdx.x * 256 + threadIdx.x;
    if (j < MSEL) {
        int r = sel[j];
        next[j] = atomicExch(head + r, j);
    }
}

// ---------------------------------------------------------------------------
// Gather -> 3-layer ELU MLP (bf16 MFMA) -> coalesced up burst.
// Block = 256 thr = 4 waves, 32 selected rows.  Wave computes ALL rows x a
// 64-col slice (32-col layer 2); B-fragments register-resident per layer.
// KEY R10 change: B1-pass0 and B2 fragment loads are hoisted ABOVE the
// barrier preceding their use (issued during the previous layer's epilogue)
// — removes the post-barrier L2-latency stall the compiler can't hoist.
// NO in-kernel x->out copy (R7/R8/R9: barriers' vmcnt(0) drain serializes
// any in-kernel streaming); merge_out does copy+add at full BW instead.
// LDS 32KB: x [0,4096) sh, h0 [4096,12288), h1 rows0-15 [12288,16384),
// rows16-31 [0,4096) (overlay; x dead after layer 0).
// XOR swizzle shortIdx ^= (row&7)<<3 breaks ds_read_b128 bank conflicts.
// NO launch_bounds wave cap (R6: forced VGPR<=102 -> spill catastrophe).
// ---------------------------------------------------------------------------
template <bool SPLIT>
__global__ __launch_bounds__(256) void mlp_compute(
    const float* __restrict__ x, const int* __restrict__ sel,
    const short* __restrict__ wp,
    const float* __restrict__ b0v, const float* __restrict__ b1v,
    const float* __restrict__ b2v,
    unsigned short* __restrict__ upOut, float* __restrict__ out) {
    __shared__ __align__(16) short lds[16384];

    const int tid  = threadIdx.x;
    const int lane = tid & 63;
    const int w    = tid >> 6;
    const int rowBase = blockIdx.x * 32;
    const int lm = lane & 15;
    const int kq = lane >> 4;
    const int sxz = (lm & 7) << 3;

    const short* W0p = wp;
    const short* W1p = wp + 32768;
    const short* W2p = wp + 98304;

    // gather loads first (longest pole: scattered HBM ~900cyc), B0 after
    const float4* xv = (const float4*)x;
    float4 gv[4];
    int grow[4], gseg[4];
    #pragma unroll
    for (int it = 0; it < 4; it++) {
        int i = it * 256 + tid;
        grow[it] = i >> 5; gseg[it] = i & 31;
        gv[it] = xv[(size_t)sel[rowBase + grow[it]] * 32 + gseg[it]];
    }

    // prefetch layer-0 B fragments (hide under gather)
    short8 B0[4][4];
    #pragma unroll
    for (int kt = 0; kt < 4; kt++)
        #pragma unroll
        for (int ntl = 0; ntl < 4; ntl++)
            B0[kt][ntl] = *(const short8*)(W0p + ((kt * 16 + (w * 4 + ntl)) * 512 + lane * 8));

    #pragma unroll
    for (int it = 0; it < 4; it++) {
        uint2v p = { pk2bf(gv[it].x, gv[it].y), pk2bf(gv[it].z, gv[it].w) };
        *(uint2v*)(&lds[(grow[it] * 128 + gseg[it] * 4) ^ ((grow[it] & 7) << 3)]) = p;
    }
    __syncthreads();

    const f32x4 zero4 = {0.f, 0.f, 0.f, 0.f};

    // ===== layer 0: (32x128) @ W0(128x256) =====
    short8 B1a[8][2];   // layer-1 pass-0 frags, hoisted across the barrier
    {
        f32x4 acc[2][4];
        #pragma unroll
        for (int i = 0; i < 2; i++)
            #pragma unroll
            for (int j = 0; j < 4; j++) acc[i][j] = zero4;
        #pragma unroll
        for (int rt = 0; rt < 2; rt++) {
            short8 a[4];
            int rowA = rt * 16 + lm;
            #pragma unroll
            for (int kt = 0; kt < 4; kt++)
                a[kt] = *(const short8*)(&lds[(rowA * 128 + kt * 32 + kq * 8) ^ sxz]);
            #pragma unroll
            for (int ntl = 0; ntl < 4; ntl++)
                #pragma unroll
                for (int kt = 0; kt < 4; kt++)
                    acc[rt][ntl] = __builtin_amdgcn_mfma_f32_16x16x32_bf16(a[kt], B0[kt][ntl], acc[rt][ntl], 0, 0, 0);
        }
        // issue B1 pass-0 loads now: latency hides under epilogue + barrier
        #pragma unroll
        for (int kt = 0; kt < 8; kt++)
            #pragma unroll
            for (int p = 0; p < 2; p++)
                B1a[kt][p] = *(const short8*)(W1p + ((kt * 16 + (w * 4 + p)) * 512 + lane * 8));

        #pragma unroll
        for (int ntl = 0; ntl < 4; ntl++) {
            int col = (w * 4 + ntl) * 16 + lm;
            float bias = b0v[col];
            #pragma unroll
            for (int rt = 0; rt < 2; rt++) {
                float v0 = elu(acc[rt][ntl][0] + bias);
                float v1 = elu(acc[rt][ntl][1] + bias);
                float v2 = elu(acc[rt][ntl][2] + bias);
                float v3 = elu(acc[rt][ntl][3] + bias);
                unsigned int u01 = pk2bf(v0, v1), u23 = pk2bf(v2, v3);
                int row = rt * 16 + kq * 4;
                lds[4096 + (((row+0) * 256 + col) ^ (((row+0) & 7) << 3))] = (short)(u01 & 0xffff);
                lds[4096 + (((row+1) * 256 + col) ^ (((row+1) & 7) << 3))] = (short)(u01 >> 16);
                lds[4096 + (((row+2) * 256 + col) ^ (((row+2) & 7) << 3))] = (short)(u23 & 0xffff);
                lds[4096 + (((row+3) * 256 + col) ^ (((row+3) & 7) << 3))] = (short)(u23 >> 16);
            }
        }
    }
    __syncthreads();

    // ===== layer 1: (32x256) @ W1(256x256) =====
    // h1 overlay: rows 0-15 -> [12288,16384), rows 16-31 -> [0,4096)
    short8 B2[8][2];    // layer-2 frags, hoisted across the post-L1 barrier
    {
        // ---- pass 0 (B1a preloaded) ----
        short8 B1b[8][2];   // pass-1 frags; issue during pass-0 MFMA
        #pragma unroll
        for (int kt = 0; kt < 8; kt++)
            #pragma unroll
            for (int p = 0; p < 2; p++)
                B1b[kt][p] = *(const short8*)(W1p + ((kt * 16 + (w * 4 + 2 + p)) * 512 + lane * 8));

        f32x4 acc[2][2];
        #pragma unroll
        for (int i = 0; i < 2; i++)
            #pragma unroll
            for (int j = 0; j < 2; j++) acc[i][j] = zero4;
        #pragma unroll
        for (int rt = 0; rt < 2; rt++) {
            short8 a[8];
            int rowA = rt * 16 + lm;
            #pragma unroll
            for (int kt = 0; kt < 8; kt++)
                a[kt] = *(const short8*)(&lds[4096 + ((rowA * 256 + kt * 32 + kq * 8) ^ sxz)]);
            #pragma unroll
            for (int p = 0; p < 2; p++)
                #pragma unroll
                for (int kt = 0; kt < 8; kt++)
                    acc[rt][p] = __builtin_amdgcn_mfma_f32_16x16x32_bf16(a[kt], B1a[kt][p], acc[rt][p], 0, 0, 0);
        }
        #pragma unroll
        for (int p = 0; p < 2; p++) {
            int col = (w * 4 + p) * 16 + lm;
            float bias = b1v[col];
            #pragma unroll
            for (int rt = 0; rt < 2; rt++) {
                float v0 = elu(acc[rt][p][0] + bias);
                float v1 = elu(acc[rt][p][1] + bias);
                float v2 = elu(acc[rt][p][2] + bias);
                float v3 = elu(acc[rt][p][3] + bias);
                unsigned int u01 = pk2bf(v0, v1), u23 = pk2bf(v2, v3);
                int row = rt * 16 + kq * 4;
                int hb = rt ? 0 : 12288;
                lds[hb + ((((row+0) & 15) * 256 + col) ^ (((row+0) & 7) << 3))] = (short)(u01 & 0xffff);
                lds[hb + ((((row+1) & 15) * 256 + col) ^ (((row+1) & 7) << 3))] = (short)(u01 >> 16);
                lds[hb + ((((row+2) & 15) * 256 + col) ^ (((row+2) & 7) << 3))] = (short)(u23 & 0xffff);
                lds[hb + ((((row+3) & 15) * 256 + col) ^ (((row+3) & 7) << 3))] = (short)(u23 >> 16);
            }
        }

        // ---- pass 1 (B1b) ----
        #pragma unroll
        for (int i = 0; i < 2; i++)
            #pragma unroll
            for (int j = 0; j < 2; j++) acc[i][j] = zero4;
        #pragma unroll
        for (int rt = 0; rt < 2; rt++) {
            short8 a[8];
            int rowA = rt * 16 + lm;
            #pragma unroll
            for (int kt = 0; kt < 8; kt++)
                a[kt] = *(const short8*)(&lds[4096 + ((rowA * 256 + kt * 32 + kq * 8) ^ sxz)]);
            #pragma unroll
            for (int p = 0; p < 2; p++)
                #pragma unroll
                for (int kt = 0; kt < 8; kt++)
                    acc[rt][p] = __builtin_amdgcn_mfma_f32_16x16x32_bf16(a[kt], B1b[kt][p], acc[rt][p], 0, 0, 0);
        }
        // issue B2 loads now: latency hides under pass-1 epilogue + barrier
        #pragma unroll
        for (int kt = 0; kt < 8; kt++)
            #pragma unroll
            for (int ntl = 0; ntl < 2; ntl++)
                B2[kt][ntl] = *(const short8*)(W2p + ((kt * 8 + (w * 2 + ntl)) * 512 + lane * 8));

        #pragma unroll
        for (int p = 0; p < 2; p++) {
            int col = (w * 4 + 2 + p) * 16 + lm;
            float bias = b1v[col];
            #pragma unroll
            for (int rt = 0; rt < 2; rt++) {
                float v0 = elu(acc[rt][p][0] + bias);
                float v1 = elu(acc[rt][p][1] + bias);
                float v2 = elu(acc[rt][p][2] + bias);
                float v3 = elu(acc[rt][p][3] + bias);
                unsigned int u01 = pk2bf(v0, v1), u23 = pk2bf(v2, v3);
                int row = rt * 16 + kq * 4;
                int hb = rt ? 0 : 12288;
                lds[hb + ((((row+0) & 15) * 256 + col) ^ (((row+0) & 7) << 3))] = (short)(u01 & 0xffff);
                lds[hb + ((((row+1) & 15) * 256 + col) ^ (((row+1) & 7) << 3))] = (short)(u01 >> 16);
                lds[hb + ((((row+2) & 15) * 256 + col) ^ (((row+2) & 7) << 3))] = (short)(u23 & 0xffff);
                lds[hb + ((((row+3) & 15) * 256 + col) ^ (((row+3) & 7) << 3))] = (short)(u23 >> 16);
            }
        }
    }
    __syncthreads();

    // ===== layer 2: (32x256) @ W2(256x128) =====
    {
        f32x4 acc[2][2];
        #pragma unroll
        for (int i = 0; i < 2; i++)
            #pragma unroll
            for (int j = 0; j < 2; j++) acc[i][j] = zero4;
        #pragma unroll
        for (int rt = 0; rt < 2; rt++) {
            short8 a[8];
            int rowA = rt * 16 + lm;
            int hb = rt ? 0 : 12288;
            #pragma unroll
            for (int kt = 0; kt < 8; kt++)
                a[kt] = *(const short8*)(&lds[hb + (((rowA & 15) * 256 + kt * 32 + kq * 8) ^ sxz)]);
            #pragma unroll
            for (int ntl = 0; ntl < 2; ntl++)
                #pragma unroll
                for (int kt = 0; kt < 8; kt++)
                    acc[rt][ntl] = __builtin_amdgcn_mfma_f32_16x16x32_bf16(a[kt], B2[kt][ntl], acc[rt][ntl], 0, 0, 0);
        }
        // epilogue 2: bias+ELU -> stage up tile in LDS (h0 region, free now)
        #pragma unroll
        for (int ntl = 0; ntl < 2; ntl++) {
            int col = (w * 2 + ntl) * 16 + lm;
            float bias = b2v[col];
            #pragma unroll
            for (int rt = 0; rt < 2; rt++)
                #pragma unroll
                for (int r = 0; r < 4; r++) {
                    int row = rt * 16 + kq * 4 + r;
                    float v = elu(acc[rt][ntl][r] + bias);
                    if (SPLIT) {
                        lds[4096 + row * 128 + col] = (short)f2bf(v);
                    } else {
                        atomicAdd(out + (size_t)sel[rowBase + row] * 128 + col, v);
                    }
                }
        }
    }
    if (SPLIT) {
        __syncthreads();
        // coalesced up write: 32 rows x 256B = 8KB contiguous, 2 dwordx4/thr
        const short8* s8 = (const short8*)(&lds[4096]);
        short8* u8 = (short8*)(upOut + (size_t)rowBase * 128);
        u8[tid]       = s8[tid];
        u8[tid + 256] = s8[tid + 256];
    }
}

// ---------------------------------------------------------------------------
// merge: wave per row, no atomics, no barriers (streaming at full BW).
// head==-1 -> out[r]=x[r]; else out[r] = x[r] + sum_{chain} up[j].
// All branches wave-uniform.
// ---------------------------------------------------------------------------
__global__ __launch_bounds__(256) void merge_out(
    const float2* __restrict__ x2, const unsigned int* __restrict__ up32,
    const int* __restrict__ head, const int* __restrict__ next,
    float2* __restrict__ out2) {
    int wid  = blockIdx.x * 4 + (threadIdx.x >> 6);
    int lane = threadIdx.x & 63;
    int wstride = gridDim.x * 4;
    for (int row = wid; row < NROWS; row += wstride) {
        float2 v = x2[(size_t)row * 64 + lane];
        int j = head[row];
        while (j >= 0) {
            unsigned int u = up32[(size_t)j * 64 + lane];
            v.x += __uint_as_float(u << 16);
            v.y += __uint_as_float(u & 0xffff0000u);
            j = next[j];
        }
        out2[(size_t)row * 64 + lane] = v;
    }
}

extern "C" void kernel_launch(void* const* d_in, const int* in_sizes, int n_in,
                              void* d_out, int out_size, void* d_ws, size_t ws_size,
                              hipStream_t stream) {
    const float* x   = (const float*)d_in[0];
    const int*   sel = (const int*)d_in[1];
    const float* W0  = (const float*)d_in[2];
    const float* b0  = (const float*)d_in[3];
    const float* W1  = (const float*)d_in[4];
    const float* b1  = (const float*)d_in[5];
    const float* W2  = (const float*)d_in[6];
    const float* b2  = (const float*)d_in[7];
    float* out = (float*)d_out;

    char* wsb = (char*)d_ws;
    short* wp          = (short*)wsb;                                  // 262144 B
    unsigned short* up = (unsigned short*)(wsb + 262144);              // 25.6 MB
    int* head          = (int*)(wsb + 262144 + (size_t)MSEL * 256);    // 1.6 MB
    int* nxt           = head + NROWS;                                 // 0.4 MB
    const size_t need  = 262144 + (size_t)MSEL * 256 + (size_t)NROWS * 4 + (size_t)MSEL * 4;

    pack_weights<<<512, 256, 0, stream>>>(W0, W1, W2, wp);
    if (ws_size >= need) {
        init_head<<<1024, 256, 0, stream>>>(head);
        build_links<<<(MSEL + 255) / 256, 256, 0, stream>>>(sel, head, nxt);
        mlp_compute<true><<<MSEL / 32, 256, 0, stream>>>(x, sel, wp, b0, b1, b2, up, out);
        merge_out<<<4096, 256, 0, stream>>>((const float2*)x, (const unsigned int*)up,
                                            head, nxt, (float2*)out);
    } else {
        copy_x<<<4096, 256, 0, stream>>>((const float4*)x, (float4*)out, NROWS * FDIM / 4);
        mlp_compute<false><<<MSEL / 32, 256, 0, stream>>>(x, sel, wp, b0, b1, b2, up, out);
    }
}